// Round 9
// baseline (1352.869 us; speedup 1.0000x reference)
//
#include <hip/hip_runtime.h>
#include <math.h>

#define N_NODES 50000
#define DIM     128
#define NHEAD   8
#define HDIM    16
#define NLAYER  2
#define NTYPE   4
#define NREL    8
#define NEDGE   800000
#define RB      256
#define GN      8      // nodes per block in grouped qkv/out kernels
#define NK      (N_NODES * NREL)

__device__ __forceinline__ float blo(unsigned w) { return __uint_as_float(w << 16); }
__device__ __forceinline__ float bhi(unsigned w) { return __uint_as_float(w & 0xFFFF0000u); }
__device__ __forceinline__ unsigned short f2bf(float f) {
    unsigned b = __float_as_uint(f);
    b += 0x7FFFu + ((b >> 16) & 1u);
    return (unsigned short)(b >> 16);
}

// ================= init: rank within type =================

__global__ void k_hist(const int* __restrict__ ntype, int* __restrict__ hist, int n) {
    __shared__ int cnt[NTYPE];
    if (threadIdx.x < NTYPE) cnt[threadIdx.x] = 0;
    __syncthreads();
    int i = blockIdx.x * RB + threadIdx.x;
    if (i < n) atomicAdd(&cnt[ntype[i]], 1);
    __syncthreads();
    if (threadIdx.x < NTYPE) hist[blockIdx.x * NTYPE + threadIdx.x] = cnt[threadIdx.x];
}

__global__ void k_prefix(const int* __restrict__ hist, int* __restrict__ off, int nb) {
    int t = threadIdx.x;
    if (t >= NTYPE) return;
    int acc = 0;
    for (int b = 0; b < nb; b++) { off[b * NTYPE + t] = acc; acc += hist[b * NTYPE + t]; }
}

__global__ void k_rank(const int* __restrict__ ntype, const int* __restrict__ off,
                       int* __restrict__ rank, int n) {
    __shared__ int ty[RB];
    int i = blockIdx.x * RB + threadIdx.x;
    int t = (i < n) ? ntype[i] : -1;
    ty[threadIdx.x] = t;
    __syncthreads();
    if (i < n) {
        int c = 0;
        for (int j = 0; j < (int)threadIdx.x; j++) c += (ty[j] == t);
        rank[i] = off[blockIdx.x * NTYPE + t] + c;
    }
}

__global__ void k_embed(const float* __restrict__ embed, const int* __restrict__ ntype,
                        const int* __restrict__ rank, float* __restrict__ h) {
    int i = blockIdx.x;
    int t = ntype[i], r = rank[i];
    h[(size_t)i * DIM + threadIdx.x] = embed[((size_t)t * N_NODES + r) * DIM + threadIdx.x];
}

__global__ void k_typeoff(const int* __restrict__ hist, const int* __restrict__ boff,
                          int nb, int* __restrict__ typeoff) {
    if (threadIdx.x == 0 && blockIdx.x == 0) {
        int acc = 0;
        for (int t = 0; t < NTYPE; t++) {
            typeoff[t] = acc;
            acc += boff[(nb - 1) * NTYPE + t] + hist[(nb - 1) * NTYPE + t];
        }
    }
}

__global__ void k_perm(const int* __restrict__ ntype, const int* __restrict__ rank,
                       const int* __restrict__ typeoff, int* __restrict__ perm, int n) {
    int i = blockIdx.x * 256 + threadIdx.x;
    if (i < n) perm[typeoff[ntype[i]] + rank[i]] = i;
}

// ================= (dst,etype)-sorted CSR build =================

__global__ void k_deg2(const int* __restrict__ dst, const int* __restrict__ etype,
                       int* __restrict__ deg) {
    int e = blockIdx.x * 256 + threadIdx.x;
    if (e < NEDGE) atomicAdd(&deg[dst[e] * NREL + etype[e]], 1);
}

__global__ void k_scan1(const int* __restrict__ deg, int* __restrict__ rs,
                        int* __restrict__ bsum, int n) {
    __shared__ int sh[256];
    int i = blockIdx.x * 256 + threadIdx.x;
    int v = (i < n) ? deg[i] : 0;
    sh[threadIdx.x] = v;
    __syncthreads();
    for (int off = 1; off < 256; off <<= 1) {
        int x = (threadIdx.x >= off) ? sh[threadIdx.x - off] : 0;
        __syncthreads();
        sh[threadIdx.x] += x;
        __syncthreads();
    }
    if (i < n) rs[i] = sh[threadIdx.x] - v;
    if (threadIdx.x == 255) bsum[blockIdx.x] = sh[255];
}

__global__ void k_scan2b(int* __restrict__ bsum, int nb) {
    __shared__ int sh[256];
    __shared__ int carry;
    if (threadIdx.x == 0) carry = 0;
    __syncthreads();
    for (int base = 0; base < nb; base += 256) {
        int i = base + threadIdx.x;
        int v = (i < nb) ? bsum[i] : 0;
        sh[threadIdx.x] = v;
        __syncthreads();
        for (int off = 1; off < 256; off <<= 1) {
            int x = (threadIdx.x >= off) ? sh[threadIdx.x - off] : 0;
            __syncthreads();
            sh[threadIdx.x] += x;
            __syncthreads();
        }
        if (i < nb) bsum[i] = sh[threadIdx.x] - v + carry;
        __syncthreads();
        if (threadIdx.x == 0) carry += sh[255];
        __syncthreads();
    }
}

__global__ void k_scan3(int* __restrict__ rs, const int* __restrict__ bsum, int n) {
    int i = blockIdx.x * 256 + threadIdx.x;
    if (i < n) rs[i] += bsum[blockIdx.x];
    if (i == 0) rs[n] = NEDGE;
}

__global__ void k_scatter2(const int* __restrict__ src, const int* __restrict__ dst,
                           const int* __restrict__ etype, const int* __restrict__ rs,
                           int* __restrict__ cur, int* __restrict__ epk) {
    int e = blockIdx.x * 256 + threadIdx.x;
    if (e < NEDGE) {
        int et = etype[e];
        int key = dst[e] * NREL + et;
        int p = atomicAdd(&cur[key], 1);
        epk[rs[key] + p] = src[e] | (et << 24);
    }
}

// ================= rmsg transpose: rmsgT[l][h][et][o][d] = rmsg[l][h][et][d][o] ====

__global__ void k_rmsgT(const float* __restrict__ rmsg, float* __restrict__ rmsgT) {
    int b = blockIdx.x;
    int d = threadIdx.x >> 4, o = threadIdx.x & 15;
    rmsgT[b * 256 + o * 16 + d] = rmsg[b * 256 + d * 16 + o];
}

// ================= typed k/q/v projection (k, v stored bf16) =================

__global__ __launch_bounds__(128) void k_qkv_g(
        const float* __restrict__ h, const int* __restrict__ perm, const int* __restrict__ ntype,
        const float* __restrict__ Wk, const float* __restrict__ Wq, const float* __restrict__ Wv,
        unsigned short* __restrict__ kb, float* __restrict__ qout,
        unsigned short* __restrict__ vb, int n) {
    int o = threadIdx.x;
    int base = blockIdx.x * GN;
    __shared__ float xs[GN][DIM];
    __shared__ int nodes[GN];
    __shared__ int types[GN];
    if (o < GN) {
        int idx = base + o;
        int nd = (idx < n) ? perm[idx] : -1;
        nodes[o] = nd;
        types[o] = (nd >= 0) ? ntype[nd] : -1;
    }
    __syncthreads();
    #pragma unroll
    for (int nn = 0; nn < GN; nn++)
        if (nodes[nn] >= 0) xs[nn][o] = h[(size_t)nodes[nn] * DIM + o];
    __syncthreads();
    bool same = (nodes[GN - 1] >= 0) && (types[0] == types[GN - 1]);
    if (same) {
        int t = types[0];
        const float* wk = Wk + (size_t)t * DIM * DIM;
        const float* wq = Wq + (size_t)t * DIM * DIM;
        const float* wv = Wv + (size_t)t * DIM * DIM;
        float ak[GN], aq[GN], av[GN];
        #pragma unroll
        for (int nn = 0; nn < GN; nn++) { ak[nn] = 0.f; aq[nn] = 0.f; av[nn] = 0.f; }
        for (int d = 0; d < DIM; d++) {
            float wkv = wk[d * DIM + o], wqv = wq[d * DIM + o], wvv = wv[d * DIM + o];
            #pragma unroll
            for (int nn = 0; nn < GN; nn++) {
                float xv = xs[nn][d];
                ak[nn] = fmaf(xv, wkv, ak[nn]);
                aq[nn] = fmaf(xv, wqv, aq[nn]);
                av[nn] = fmaf(xv, wvv, av[nn]);
            }
        }
        #pragma unroll
        for (int nn = 0; nn < GN; nn++) {
            size_t p = (size_t)nodes[nn] * DIM + o;
            kb[p] = f2bf(ak[nn]); qout[p] = aq[nn]; vb[p] = f2bf(av[nn]);
        }
    } else {
        #pragma unroll 1
        for (int nn = 0; nn < GN; nn++) {
            if (nodes[nn] < 0) continue;
            int t = types[nn];
            const float* wk = Wk + (size_t)t * DIM * DIM;
            const float* wq = Wq + (size_t)t * DIM * DIM;
            const float* wv = Wv + (size_t)t * DIM * DIM;
            float ak = 0.f, aq = 0.f, av = 0.f;
            for (int d = 0; d < DIM; d++) {
                float xv = xs[nn][d];
                ak = fmaf(xv, wk[d * DIM + o], ak);
                aq = fmaf(xv, wq[d * DIM + o], aq);
                av = fmaf(xv, wv[d * DIM + o], av);
            }
            size_t p = (size_t)nodes[nn] * DIM + o;
            kb[p] = f2bf(ak); qout[p] = aq; vb[p] = f2bf(av);
        }
    }
}

// ================= fused attention v8 =================
// fused5 schedule (homogeneous branch-free pass-2, loads batched) + register buckets:
// fixed 16-trip unrolled pass-2; bucket select via 8 compare-adds (no branches at all);
// invalid lanes carry p=0 / sv=0 so no masking needed. Zero __syncthreads.

__global__ __launch_bounds__(128) void k_fused8(
        const unsigned short* __restrict__ kb, const unsigned short* __restrict__ vb,
        const float* __restrict__ qbuf,
        const int* __restrict__ rs2, const int* __restrict__ epk,
        const float* __restrict__ ratt, const float* __restrict__ rmsgT,
        const float* __restrict__ rpri, float* __restrict__ agg) {
    int node = blockIdx.x;
    int tid = threadIdx.x;
    int hh = tid >> 4, oo = tid & 15;
    int wv = tid >> 6;            // wave id
    int hl = hh & 3;              // head local to wave

    __shared__ float q_s[DIM];
    __shared__ float u_s[NREL][NHEAD * HDIM + 4];   // stride 132, 16B-aligned rows
    __shared__ float B_s[NREL][NHEAD * HDIM + 4];   // flush staging
    __shared__ float a_sw[2][4][HDIM + 1];          // per-wave p scratch
    __shared__ int   es_sw[2][HDIM];                // per-wave packed-edge scratch

    int e0 = rs2[node * NREL];
    int e1 = rs2[node * NREL + NREL];
    if (e0 == e1) { agg[(size_t)node * DIM + tid] = 0.f; return; }

    q_s[tid] = qbuf[(size_t)node * DIM + tid];
    // u_s[et][hh*16+d] = (ratt[hh][et][d][:] . q_h) * pri * 0.25  (lane d = oo), all et
    {
        const float4* q4 = (const float4*)&q_s[hh * HDIM];   // intra-group LDS, in-order
        float4 q0 = q4[0], q1 = q4[1], q2 = q4[2], q3 = q4[3];
        #pragma unroll
        for (int et = 0; et < NREL; et++) {
            const float4* w4 = (const float4*)(ratt + ((size_t)(hh * NREL + et) * HDIM + oo) * HDIM);
            float4 w0 = w4[0], w1 = w4[1], w2 = w4[2], w3 = w4[3];
            float s = w0.x*q0.x + w0.y*q0.y + w0.z*q0.z + w0.w*q0.w
                    + w1.x*q1.x + w1.y*q1.y + w1.z*q1.z + w1.w*q1.w
                    + w2.x*q2.x + w2.y*q2.y + w2.z*q2.z + w2.w*q2.w
                    + w3.x*q3.x + w3.y*q3.y + w3.z*q3.z + w3.w*q3.w;
            u_s[et][tid] = s * rpri[hh * NREL + et] * 0.25f;
        }
    }

    float m_h = -1e30f, s_h = 0.f;
    float B0 = 0.f, B1 = 0.f, B2 = 0.f, B3 = 0.f,
          B4 = 0.f, B5 = 0.f, B6 = 0.f, B7 = 0.f;

    for (int w0e = e0; w0e < e1; w0e += HDIM) {
        int cnt = min(HDIM, e1 - w0e);
        // ---- pass 1: logits + deferred-rescale online softmax ----
        float a = -1e30f;
        int pk = 0;
        if (oo < cnt) {
            pk = epk[w0e + oo];
            int sv = pk & 0x00FFFFFF;
            int et = ((unsigned)pk) >> 24;
            const uint4* kr = (const uint4*)(kb + (size_t)sv * DIM + hh * HDIM);
            uint4 ka = kr[0], kc = kr[1];
            const float4* u4 = (const float4*)&u_s[et][hh * HDIM];
            float4 u0 = u4[0], u1 = u4[1], u2 = u4[2], u3 = u4[3];
            a = blo(ka.x)*u0.x + bhi(ka.x)*u0.y + blo(ka.y)*u0.z + bhi(ka.y)*u0.w
              + blo(ka.z)*u1.x + bhi(ka.z)*u1.y + blo(ka.w)*u1.z + bhi(ka.w)*u1.w
              + blo(kc.x)*u2.x + bhi(kc.x)*u2.y + blo(kc.y)*u2.z + bhi(kc.y)*u2.w
              + blo(kc.z)*u3.x + bhi(kc.z)*u3.y + blo(kc.w)*u3.z + bhi(kc.w)*u3.w;
        }
        if (hl == 0) es_sw[wv][oo] = pk;
        float cmax = a;
        cmax = fmaxf(cmax, __shfl_xor(cmax, 1));
        cmax = fmaxf(cmax, __shfl_xor(cmax, 2));
        cmax = fmaxf(cmax, __shfl_xor(cmax, 4));
        cmax = fmaxf(cmax, __shfl_xor(cmax, 8));
        float m_t = (cmax > m_h + 12.f) ? cmax : m_h;   // deferred rescale (THR=12)
        float r = __expf(m_h - m_t);                    // ==1 when not triggered
        s_h *= r; m_h = m_t;
        B0 *= r; B1 *= r; B2 *= r; B3 *= r; B4 *= r; B5 *= r; B6 *= r; B7 *= r;
        float p = (oo < cnt) ? __expf(a - m_h) : 0.f;
        float ps = p;
        ps += __shfl_xor(ps, 1);
        ps += __shfl_xor(ps, 2);
        ps += __shfl_xor(ps, 4);
        ps += __shfl_xor(ps, 8);
        s_h += ps;
        a_sw[wv][hl][oo] = p;
        // ---- pass 2: fixed-trip, branch-free; 16 loads batched in flight ----
        #pragma unroll
        for (int c = 0; c < HDIM; c++) {
            float pc = a_sw[wv][hl][c];              // 0 for c >= cnt
            int pkc = es_sw[wv][c];                  // 0 for c >= cnt -> sv = 0 (benign)
            int sv = pkc & 0x00FFFFFF;
            int etc = (int)(((unsigned)pkc) >> 24);
            unsigned short uv = vb[(size_t)sv * DIM + tid];   // coalesced bf16
            float pv = pc * __uint_as_float((unsigned)uv << 16);
            B0 += (etc == 0) ? pv : 0.f;
            B1 += (etc == 1) ? pv : 0.f;
            B2 += (etc == 2) ? pv : 0.f;
            B3 += (etc == 3) ? pv : 0.f;
            B4 += (etc == 4) ? pv : 0.f;
            B5 += (etc == 5) ? pv : 0.f;
            B6 += (etc == 6) ? pv : 0.f;
            B7 += (etc == 7) ? pv : 0.f;
        }
    }

    // ---- W_msg flush (intra-group LDS only), unconditional over all et ----
    B_s[0][tid] = B0; B_s[1][tid] = B1; B_s[2][tid] = B2; B_s[3][tid] = B3;
    B_s[4][tid] = B4; B_s[5][tid] = B5; B_s[6][tid] = B6; B_s[7][tid] = B7;
    float out = 0.f;
    #pragma unroll
    for (int et = 0; et < NREL; et++) {
        const float4* w4 = (const float4*)(rmsgT + ((size_t)(hh * NREL + et) * HDIM + oo) * HDIM);
        float4 w0 = w4[0], w1 = w4[1], w2 = w4[2], w3 = w4[3];
        const float4* b4 = (const float4*)&B_s[et][hh * HDIM];
        float4 b0 = b4[0], b1 = b4[1], b2 = b4[2], b3 = b4[3];
        out += b0.x*w0.x + b0.y*w0.y + b0.z*w0.z + b0.w*w0.w
             + b1.x*w1.x + b1.y*w1.y + b1.z*w1.z + b1.w*w1.w
             + b2.x*w2.x + b2.y*w2.y + b2.z*w2.z + b2.w*w2.w
             + b3.x*w3.x + b3.y*w3.y + b3.z*w3.z + b3.w*w3.w;
    }
    agg[(size_t)node * DIM + tid] = out / (s_h + 1e-9f);
}

// ================= output projection + skip + LayerNorm + residual, grouped =================

__global__ __launch_bounds__(128) void k_out_g(
        const float* __restrict__ agg, float* __restrict__ h,
        const int* __restrict__ perm, const int* __restrict__ ntype,
        const float* __restrict__ Wa, const float* __restrict__ skip,
        const float* __restrict__ ln_g, const float* __restrict__ ln_b, int n) {
    int o = threadIdx.x;
    int base = blockIdx.x * GN;
    __shared__ float xs[GN][DIM];
    __shared__ float hcs[GN][DIM + 1];
    __shared__ int nodes[GN];
    __shared__ int types[GN];
    __shared__ float mu_s[GN], rs_s[GN];
    if (o < GN) {
        int idx = base + o;
        int nd = (idx < n) ? perm[idx] : -1;
        nodes[o] = nd;
        types[o] = (nd >= 0) ? ntype[nd] : -1;
    }
    __syncthreads();
    #pragma unroll
    for (int nn = 0; nn < GN; nn++)
        if (nodes[nn] >= 0) xs[nn][o] = agg[(size_t)nodes[nn] * DIM + o];
    __syncthreads();
    bool same = (nodes[GN - 1] >= 0) && (types[0] == types[GN - 1]);
    if (same) {
        int t = types[0];
        const float* w = Wa + (size_t)t * DIM * DIM;
        float acc[GN];
        #pragma unroll
        for (int nn = 0; nn < GN; nn++) acc[nn] = 0.f;
        for (int d = 0; d < DIM; d++) {
            float wv = w[d * DIM + o];
            #pragma unroll
            for (int nn = 0; nn < GN; nn++) acc[nn] = fmaf(xs[nn][d], wv, acc[nn]);
        }
        float alpha = 1.f / (1.f + __expf(-skip[t]));
        #pragma unroll
        for (int nn = 0; nn < GN; nn++) {
            float hp = h[(size_t)nodes[nn] * DIM + o];
            hcs[nn][o] = acc[nn] * alpha + hp * (1.f - alpha);
        }
    } else {
        #pragma unroll 1
        for (int nn = 0; nn < GN; nn++) {
            if (nodes[nn] < 0) continue;
            int t = types[nn];
            const float* w = Wa + (size_t)t * DIM * DIM;
            float a0 = 0.f;
            for (int d = 0; d < DIM; d++) a0 = fmaf(xs[nn][d], w[d * DIM + o], a0);
            float alpha = 1.f / (1.f + __expf(-skip[t]));
            float hp = h[(size_t)nodes[nn] * DIM + o];
            hcs[nn][o] = a0 * alpha + hp * (1.f - alpha);
        }
    }
    __syncthreads();
    {
        int g = o >> 4, j = o & 15;    // 8 groups x 16 lanes
        if (nodes[g] >= 0) {
            float s = 0.f;
            for (int d = j; d < DIM; d += 16) s += hcs[g][d];
            #pragma unroll
            for (int m = 1; m < 16; m <<= 1) s += __shfl_xor(s, m);
            float mu = s * (1.f / DIM);
            float v = 0.f;
            for (int d = j; d < DIM; d += 16) { float dv = hcs[g][d] - mu; v = fmaf(dv, dv, v); }
            #pragma unroll
            for (int m = 1; m < 16; m <<= 1) v += __shfl_xor(v, m);
            if (j == 0) { mu_s[g] = mu; rs_s[g] = rsqrtf(v * (1.f / DIM) + 1e-5f); }
        }
    }
    __syncthreads();
    float g_o = ln_g[o], b_o = ln_b[o];
    #pragma unroll
    for (int nn = 0; nn < GN; nn++) {
        if (nodes[nn] >= 0) {
            float hp = h[(size_t)nodes[nn] * DIM + o];
            h[(size_t)nodes[nn] * DIM + o] = (hcs[nn][o] - mu_s[nn]) * rs_s[nn] * g_o + b_o + hp;
        }
    }
}

// ================= host =================

extern "C" void kernel_launch(void* const* d_in, const int* in_sizes, int n_in,
                              void* d_out, int out_size, void* d_ws, size_t ws_size,
                              hipStream_t stream) {
    const float* embed = (const float*)d_in[0];
    const float* Wk    = (const float*)d_in[1];
    const float* Wq    = (const float*)d_in[2];
    const float* Wv    = (const float*)d_in[3];
    const float* Wa    = (const float*)d_in[4];
    const float* ratt  = (const float*)d_in[5];
    const float* rmsg  = (const float*)d_in[6];
    const float* rpri  = (const float*)d_in[7];
    const float* skip  = (const float*)d_in[8];
    const float* ln_g  = (const float*)d_in[9];
    const float* ln_b  = (const float*)d_in[10];
    const int*   src   = (const int*)d_in[11];
    const int*   dst   = (const int*)d_in[12];
    const int*   ntype = (const int*)d_in[13];
    const int*   etype = (const int*)d_in[14];

    float* h = (float*)d_out;

    const size_t ND = (size_t)N_NODES * DIM;
    const int nb = (N_NODES + RB - 1) / RB;
    unsigned short* kb = (unsigned short*)d_ws;          // N*128 bf16
    unsigned short* vb = kb + ND;                        // N*128 bf16
    float* qbuf = (float*)(vb + ND);                     // N*128 fp32
    int* rs2  = (int*)(qbuf + ND);               // NK+1
    int* deg2 = rs2 + (NK + 1);                  // NK
    int* cur2 = deg2 + NK;                       // NK
    int* epk  = cur2 + NK;                       // E
    int* bsum = epk + NEDGE;                     // 2048
    int* rank = bsum + 2048;                     // N
    int* hist = rank + N_NODES;                  // nb*NTYPE
    int* boff = hist + nb * NTYPE;               // nb*NTYPE
    int* typeoff = boff + nb * NTYPE;            // NTYPE
    int* perm = typeoff + NTYPE;                 // N
    float* rmsgT = (float*)(perm + N_NODES);     // L*H*R*256
    float* agg = qbuf;                           // alias: block reads its q row, then writes agg row

    const int EB = (NEDGE + 255) / 256;
    const int nb2 = (NK + 255) / 256;

    // ---- init: rank-within-type, embedding, type permutation ----
    k_hist<<<nb, RB, 0, stream>>>(ntype, hist, N_NODES);
    k_prefix<<<1, 64, 0, stream>>>(hist, boff, nb);
    k_rank<<<nb, RB, 0, stream>>>(ntype, boff, rank, N_NODES);
    k_embed<<<N_NODES, DIM, 0, stream>>>(embed, ntype, rank, h);
    k_typeoff<<<1, 64, 0, stream>>>(hist, boff, nb, typeoff);
    k_perm<<<nb, 256, 0, stream>>>(ntype, rank, typeoff, perm, N_NODES);

    // ---- (dst,etype)-sorted CSR build (graph static across layers) ----
    hipMemsetAsync(deg2, 0, (size_t)NK * sizeof(int), stream);
    hipMemsetAsync(cur2, 0, (size_t)NK * sizeof(int), stream);
    k_deg2<<<EB, 256, 0, stream>>>(dst, etype, deg2);
    k_scan1<<<nb2, 256, 0, stream>>>(deg2, rs2, bsum, NK);
    k_scan2b<<<1, 256, 0, stream>>>(bsum, nb2);
    k_scan3<<<nb2, 256, 0, stream>>>(rs2, bsum, NK);
    k_scatter2<<<EB, 256, 0, stream>>>(src, dst, etype, rs2, cur2, epk);

    // ---- rmsg transpose (all layers) ----
    k_rmsgT<<<NLAYER * NHEAD * NREL, 256, 0, stream>>>(rmsg, rmsgT);

    const int NGB = N_NODES / GN;   // 6250

    for (int l = 0; l < NLAYER; l++) {
        const float* Wk_l = Wk + (size_t)l * NTYPE * DIM * DIM;
        const float* Wq_l = Wq + (size_t)l * NTYPE * DIM * DIM;
        const float* Wv_l = Wv + (size_t)l * NTYPE * DIM * DIM;
        const float* Wa_l = Wa + (size_t)l * NTYPE * DIM * DIM;
        const float* ratt_l = ratt + (size_t)l * NHEAD * NREL * HDIM * HDIM;
        const float* rmsgT_l = rmsgT + (size_t)l * NHEAD * NREL * HDIM * HDIM;
        const float* rpri_l = rpri + (size_t)l * NHEAD * NREL;
        const float* skip_l = skip + (size_t)l * NTYPE;
        const float* g_l = ln_g + (size_t)l * DIM;
        const float* b_l = ln_b + (size_t)l * DIM;

        k_qkv_g<<<NGB, 128, 0, stream>>>(h, perm, ntype, Wk_l, Wq_l, Wv_l,
                                         kb, qbuf, vb, N_NODES);
        k_fused8<<<N_NODES, 128, 0, stream>>>(kb, vb, qbuf, rs2, epk,
                                              ratt_l, rmsgT_l, rpri_l, agg);
        k_out_g<<<NGB, 128, 0, stream>>>(agg, h, perm, ntype, Wa_l, skip_l, g_l, b_l, N_NODES);
    }
}

// Round 10
// 990.593 us; speedup vs baseline: 1.3657x; 1.3657x over previous
//
#include <hip/hip_runtime.h>
#include <math.h>

#define N_NODES 50000
#define DIM     128
#define NHEAD   8
#define HDIM    16
#define NLAYER  2
#define NTYPE   4
#define NREL    8
#define NEDGE   800000
#define RB      256
#define GN      8      // nodes per block in grouped qkv/out/vt kernels
#define NK      (N_NODES * NREL)

__device__ __forceinline__ float blo(unsigned w) { return __uint_as_float(w << 16); }
__device__ __forceinline__ float bhi(unsigned w) { return __uint_as_float(w & 0xFFFF0000u); }
__device__ __forceinline__ unsigned short f2bf(float f) {
    unsigned b = __float_as_uint(f);
    b += 0x7FFFu + ((b >> 16) & 1u);
    return (unsigned short)(b >> 16);
}

// ================= init: rank within type =================

__global__ void k_hist(const int* __restrict__ ntype, int* __restrict__ hist, int n) {
    __shared__ int cnt[NTYPE];
    if (threadIdx.x < NTYPE) cnt[threadIdx.x] = 0;
    __syncthreads();
    int i = blockIdx.x * RB + threadIdx.x;
    if (i < n) atomicAdd(&cnt[ntype[i]], 1);
    __syncthreads();
    if (threadIdx.x < NTYPE) hist[blockIdx.x * NTYPE + threadIdx.x] = cnt[threadIdx.x];
}

__global__ void k_prefix(const int* __restrict__ hist, int* __restrict__ off, int nb) {
    int t = threadIdx.x;
    if (t >= NTYPE) return;
    int acc = 0;
    for (int b = 0; b < nb; b++) { off[b * NTYPE + t] = acc; acc += hist[b * NTYPE + t]; }
}

__global__ void k_rank(const int* __restrict__ ntype, const int* __restrict__ off,
                       int* __restrict__ rank, int n) {
    __shared__ int ty[RB];
    int i = blockIdx.x * RB + threadIdx.x;
    int t = (i < n) ? ntype[i] : -1;
    ty[threadIdx.x] = t;
    __syncthreads();
    if (i < n) {
        int c = 0;
        for (int j = 0; j < (int)threadIdx.x; j++) c += (ty[j] == t);
        rank[i] = off[blockIdx.x * NTYPE + t] + c;
    }
}

__global__ void k_embed(const float* __restrict__ embed, const int* __restrict__ ntype,
                        const int* __restrict__ rank, float* __restrict__ h) {
    int i = blockIdx.x;
    int t = ntype[i], r = rank[i];
    h[(size_t)i * DIM + threadIdx.x] = embed[((size_t)t * N_NODES + r) * DIM + threadIdx.x];
}

__global__ void k_typeoff(const int* __restrict__ hist, const int* __restrict__ boff,
                          int nb, int* __restrict__ typeoff) {
    if (threadIdx.x == 0 && blockIdx.x == 0) {
        int acc = 0;
        for (int t = 0; t < NTYPE; t++) {
            typeoff[t] = acc;
            acc += boff[(nb - 1) * NTYPE + t] + hist[(nb - 1) * NTYPE + t];
        }
    }
}

__global__ void k_perm(const int* __restrict__ ntype, const int* __restrict__ rank,
                       const int* __restrict__ typeoff, int* __restrict__ perm, int n) {
    int i = blockIdx.x * 256 + threadIdx.x;
    if (i < n) perm[typeoff[ntype[i]] + rank[i]] = i;
}

// ================= (dst,etype)-sorted CSR build =================

__global__ void k_deg2(const int* __restrict__ dst, const int* __restrict__ etype,
                       int* __restrict__ deg) {
    int e = blockIdx.x * 256 + threadIdx.x;
    if (e < NEDGE) atomicAdd(&deg[dst[e] * NREL + etype[e]], 1);
}

__global__ void k_scan1(const int* __restrict__ deg, int* __restrict__ rs,
                        int* __restrict__ bsum, int n) {
    __shared__ int sh[256];
    int i = blockIdx.x * 256 + threadIdx.x;
    int v = (i < n) ? deg[i] : 0;
    sh[threadIdx.x] = v;
    __syncthreads();
    for (int off = 1; off < 256; off <<= 1) {
        int x = (threadIdx.x >= off) ? sh[threadIdx.x - off] : 0;
        __syncthreads();
        sh[threadIdx.x] += x;
        __syncthreads();
    }
    if (i < n) rs[i] = sh[threadIdx.x] - v;
    if (threadIdx.x == 255) bsum[blockIdx.x] = sh[255];
}

__global__ void k_scan2b(int* __restrict__ bsum, int nb) {
    __shared__ int sh[256];
    __shared__ int carry;
    if (threadIdx.x == 0) carry = 0;
    __syncthreads();
    for (int base = 0; base < nb; base += 256) {
        int i = base + threadIdx.x;
        int v = (i < nb) ? bsum[i] : 0;
        sh[threadIdx.x] = v;
        __syncthreads();
        for (int off = 1; off < 256; off <<= 1) {
            int x = (threadIdx.x >= off) ? sh[threadIdx.x - off] : 0;
            __syncthreads();
            sh[threadIdx.x] += x;
            __syncthreads();
        }
        if (i < nb) bsum[i] = sh[threadIdx.x] - v + carry;
        __syncthreads();
        if (threadIdx.x == 0) carry += sh[255];
        __syncthreads();
    }
}

__global__ void k_scan3(int* __restrict__ rs, const int* __restrict__ bsum, int n) {
    int i = blockIdx.x * 256 + threadIdx.x;
    if (i < n) rs[i] += bsum[blockIdx.x];
    if (i == 0) rs[n] = NEDGE;
}

__global__ void k_scatter2(const int* __restrict__ src, const int* __restrict__ dst,
                           const int* __restrict__ etype, const int* __restrict__ rs,
                           int* __restrict__ cur, int* __restrict__ epk) {
    int e = blockIdx.x * 256 + threadIdx.x;
    if (e < NEDGE) {
        int et = etype[e];
        int key = dst[e] * NREL + et;
        int p = atomicAdd(&cur[key], 1);
        epk[rs[key] + p] = src[e] | (et << 24);
    }
}

// ================= weight prep: rmsgT transpose + bf16 ratt pack =================

__global__ void k_rmsgT(const float* __restrict__ rmsg, float* __restrict__ rmsgT) {
    int b = blockIdx.x;
    int d = threadIdx.x >> 4, o = threadIdx.x & 15;
    rmsgT[b * 256 + o * 16 + d] = rmsg[b * 256 + d * 16 + o];
}

__global__ void k_rattB(const float* __restrict__ ratt, unsigned short* __restrict__ rattB) {
    int i = blockIdx.x * 256 + threadIdx.x;
    rattB[i] = f2bf(ratt[i]);
}

// ================= typed k/q/v projection (k bf16, q/v fp32) =================

__global__ __launch_bounds__(128) void k_qkv_g(
        const float* __restrict__ h, const int* __restrict__ perm, const int* __restrict__ ntype,
        const float* __restrict__ Wk, const float* __restrict__ Wq, const float* __restrict__ Wv,
        unsigned short* __restrict__ kb, float* __restrict__ qout, float* __restrict__ vout, int n) {
    int o = threadIdx.x;
    int base = blockIdx.x * GN;
    __shared__ float xs[GN][DIM];
    __shared__ int nodes[GN];
    __shared__ int types[GN];
    if (o < GN) {
        int idx = base + o;
        int nd = (idx < n) ? perm[idx] : -1;
        nodes[o] = nd;
        types[o] = (nd >= 0) ? ntype[nd] : -1;
    }
    __syncthreads();
    #pragma unroll
    for (int nn = 0; nn < GN; nn++)
        if (nodes[nn] >= 0) xs[nn][o] = h[(size_t)nodes[nn] * DIM + o];
    __syncthreads();
    bool same = (nodes[GN - 1] >= 0) && (types[0] == types[GN - 1]);
    if (same) {
        int t = types[0];
        const float* wk = Wk + (size_t)t * DIM * DIM;
        const float* wq = Wq + (size_t)t * DIM * DIM;
        const float* wv = Wv + (size_t)t * DIM * DIM;
        float ak[GN], aq[GN], av[GN];
        #pragma unroll
        for (int nn = 0; nn < GN; nn++) { ak[nn] = 0.f; aq[nn] = 0.f; av[nn] = 0.f; }
        for (int d = 0; d < DIM; d++) {
            float wkv = wk[d * DIM + o], wqv = wq[d * DIM + o], wvv = wv[d * DIM + o];
            #pragma unroll
            for (int nn = 0; nn < GN; nn++) {
                float xv = xs[nn][d];
                ak[nn] = fmaf(xv, wkv, ak[nn]);
                aq[nn] = fmaf(xv, wqv, aq[nn]);
                av[nn] = fmaf(xv, wvv, av[nn]);
            }
        }
        #pragma unroll
        for (int nn = 0; nn < GN; nn++) {
            size_t p = (size_t)nodes[nn] * DIM + o;
            kb[p] = f2bf(ak[nn]); qout[p] = aq[nn]; vout[p] = av[nn];
        }
    } else {
        #pragma unroll 1
        for (int nn = 0; nn < GN; nn++) {
            if (nodes[nn] < 0) continue;
            int t = types[nn];
            const float* wk = Wk + (size_t)t * DIM * DIM;
            const float* wq = Wq + (size_t)t * DIM * DIM;
            const float* wv = Wv + (size_t)t * DIM * DIM;
            float ak = 0.f, aq = 0.f, av = 0.f;
            for (int d = 0; d < DIM; d++) {
                float xv = xs[nn][d];
                ak = fmaf(xv, wk[d * DIM + o], ak);
                aq = fmaf(xv, wq[d * DIM + o], aq);
                av = fmaf(xv, wv[d * DIM + o], av);
            }
            size_t p = (size_t)nodes[nn] * DIM + o;
            kb[p] = f2bf(ak); qout[p] = aq; vout[p] = av;
        }
    }
}

// ================= vt build: vt[n][et][h*16+o] = bf16( sum_d v[n][h*16+d] * rmsg[h][et][d][o] ) ==

__global__ __launch_bounds__(128) void k_vt(
        const float* __restrict__ vbuf, const float* __restrict__ rmsgT,
        unsigned short* __restrict__ vt) {
    int tid = threadIdx.x;
    int hh = tid >> 4, oo = tid & 15;
    int base = blockIdx.x * GN;
    __shared__ float v_s[GN][DIM];
    #pragma unroll
    for (int nn = 0; nn < GN; nn++)
        v_s[nn][tid] = vbuf[(size_t)(base + nn) * DIM + tid];
    __syncthreads();
    #pragma unroll 1
    for (int et = 0; et < NREL; et++) {
        const float4* w4 = (const float4*)(rmsgT + ((size_t)(hh * NREL + et) * HDIM + oo) * HDIM);
        float4 w0 = w4[0], w1 = w4[1], w2 = w4[2], w3 = w4[3];
        #pragma unroll
        for (int nn = 0; nn < GN; nn++) {
            const float4* v4 = (const float4*)&v_s[nn][hh * HDIM];
            float4 v0 = v4[0], v1 = v4[1], v2 = v4[2], v3 = v4[3];
            float acc = v0.x*w0.x + v0.y*w0.y + v0.z*w0.z + v0.w*w0.w
                      + v1.x*w1.x + v1.y*w1.y + v1.z*w1.z + v1.w*w1.w
                      + v2.x*w2.x + v2.y*w2.y + v2.z*w2.z + v2.w*w2.w
                      + v3.x*w3.x + v3.y*w3.y + v3.z*w3.z + v3.w*w3.w;
            vt[((size_t)(base + nn) * NREL + et) * DIM + tid] = f2bf(acc);
        }
    }
}

// ================= fused attention v9: 2 nodes/block, bf16 ratt, vt pass-2 ====
// fused5 schedule (single accumulator, runtime-bounded pass-2, zero barriers in edge loop)
// + bf16 weight rows hoisted across the 2 nodes (u-compute weight traffic /4 vs fused5).

__global__ __launch_bounds__(128) void k_fused9(
        const unsigned short* __restrict__ kb, const float* __restrict__ qbuf,
        const unsigned short* __restrict__ vt,
        const int* __restrict__ rs2, const int* __restrict__ epk,
        const unsigned short* __restrict__ rattB, const float* __restrict__ rpri,
        float* __restrict__ agg) {
    int tid = threadIdx.x;
    int hh = tid >> 4, oo = tid & 15;
    int wv = tid >> 6;            // wave id (heads 0-3 | 4-7)
    int hl = hh & 3;              // head local to wave
    int n0 = blockIdx.x * 2;

    __shared__ float q_s[2][DIM];
    __shared__ float u_s[2][NREL][NHEAD * HDIM + 4];  // stride 132, 16B-aligned rows
    __shared__ float a_sw[2][4][HDIM + 1];            // per-wave p scratch (reused per node)
    __shared__ int   es_sw[2][HDIM];                  // per-wave packed-edge scratch

    q_s[0][tid] = qbuf[(size_t)n0 * DIM + tid];
    q_s[1][tid] = qbuf[(size_t)(n0 + 1) * DIM + tid];

    // q rows for this head, both nodes (intra-group LDS, in-order)
    const float4* qa4 = (const float4*)&q_s[0][hh * HDIM];
    float4 A0 = qa4[0], A1 = qa4[1], A2 = qa4[2], A3 = qa4[3];
    const float4* qb4 = (const float4*)&q_s[1][hh * HDIM];
    float4 C0 = qb4[0], C1 = qb4[1], C2 = qb4[2], C3 = qb4[3];

    // u_s[n][et][hh*16+d] = (rattB[hh][et][d][:] . q_h(n)) * pri * 0.25  (lane d = oo)
    // weight row loaded ONCE per et, used for both nodes.
    #pragma unroll
    for (int et = 0; et < NREL; et++) {
        const uint4* wB = (const uint4*)(rattB + ((size_t)(hh * NREL + et) * HDIM + oo) * HDIM);
        uint4 wa = wB[0], wb = wB[1];
        float pri = rpri[hh * NREL + et] * 0.25f;
        float u0 = blo(wa.x)*A0.x + bhi(wa.x)*A0.y + blo(wa.y)*A0.z + bhi(wa.y)*A0.w
                 + blo(wa.z)*A1.x + bhi(wa.z)*A1.y + blo(wa.w)*A1.z + bhi(wa.w)*A1.w
                 + blo(wb.x)*A2.x + bhi(wb.x)*A2.y + blo(wb.y)*A2.z + bhi(wb.y)*A2.w
                 + blo(wb.z)*A3.x + bhi(wb.z)*A3.y + blo(wb.w)*A3.z + bhi(wb.w)*A3.w;
        float u1 = blo(wa.x)*C0.x + bhi(wa.x)*C0.y + blo(wa.y)*C0.z + bhi(wa.y)*C0.w
                 + blo(wa.z)*C1.x + bhi(wa.z)*C1.y + blo(wa.w)*C1.z + bhi(wa.w)*C1.w
                 + blo(wb.x)*C2.x + bhi(wb.x)*C2.y + blo(wb.y)*C2.z + bhi(wb.y)*C2.w
                 + blo(wb.z)*C3.x + bhi(wb.z)*C3.y + blo(wb.w)*C3.z + bhi(wb.w)*C3.w;
        u_s[0][et][tid] = u0 * pri;
        u_s[1][et][tid] = u1 * pri;
    }

    #pragma unroll 1
    for (int nn = 0; nn < 2; nn++) {
        int node = n0 + nn;
        int e0 = rs2[node * NREL];
        int e1 = rs2[node * NREL + NREL];
        if (e0 == e1) { agg[(size_t)node * DIM + tid] = 0.f; continue; }

        float m_h = -1e30f, s_h = 0.f, out = 0.f;

        for (int w0e = e0; w0e < e1; w0e += HDIM) {
            int cnt = min(HDIM, e1 - w0e);
            // ---- pass 1: logits + deferred-rescale online softmax ----
            float a = -1e30f;
            int pk = 0;
            if (oo < cnt) {
                pk = epk[w0e + oo];
                int sv = pk & 0x00FFFFFF;
                int et = ((unsigned)pk) >> 24;
                const uint4* kr = (const uint4*)(kb + (size_t)sv * DIM + hh * HDIM);
                uint4 ka = kr[0], kc = kr[1];
                const float4* u4 = (const float4*)&u_s[nn][et][hh * HDIM];
                float4 u0 = u4[0], u1 = u4[1], u2 = u4[2], u3 = u4[3];
                a = blo(ka.x)*u0.x + bhi(ka.x)*u0.y + blo(ka.y)*u0.z + bhi(ka.y)*u0.w
                  + blo(ka.z)*u1.x + bhi(ka.z)*u1.y + blo(ka.w)*u1.z + bhi(ka.w)*u1.w
                  + blo(kc.x)*u2.x + bhi(kc.x)*u2.y + blo(kc.y)*u2.z + bhi(kc.y)*u2.w
                  + blo(kc.z)*u3.x + bhi(kc.z)*u3.y + blo(kc.w)*u3.z + bhi(kc.w)*u3.w;
            }
            if (hl == 0) es_sw[wv][oo] = pk;
            float cmax = a;
            cmax = fmaxf(cmax, __shfl_xor(cmax, 1));
            cmax = fmaxf(cmax, __shfl_xor(cmax, 2));
            cmax = fmaxf(cmax, __shfl_xor(cmax, 4));
            cmax = fmaxf(cmax, __shfl_xor(cmax, 8));
            float m_t = (cmax > m_h + 12.f) ? cmax : m_h;   // deferred rescale (THR=12)
            float r = __expf(m_h - m_t);                    // ==1 when not triggered
            s_h *= r; out *= r; m_h = m_t;
            float p = (oo < cnt) ? __expf(a - m_h) : 0.f;
            float ps = p;
            ps += __shfl_xor(ps, 1);
            ps += __shfl_xor(ps, 2);
            ps += __shfl_xor(ps, 4);
            ps += __shfl_xor(ps, 8);
            s_h += ps;
            a_sw[wv][hl][oo] = p;
            // ---- pass 2: runtime-bounded loop (fused5 schedule), single accumulator ----
            for (int c = 0; c < cnt; c++) {
                float pc = a_sw[wv][hl][c];        // group broadcast
                int pkc = es_sw[wv][c];            // wave broadcast
                int sv = pkc & 0x00FFFFFF;
                int et = ((unsigned)pkc) >> 24;
                unsigned short uv = vt[((size_t)sv * NREL + et) * DIM + tid];
                out = fmaf(pc, __uint_as_float((unsigned)uv << 16), out);
            }
        }

        agg[(size_t)node * DIM + tid] = out / (s_h + 1e-9f);
    }
}

// ================= output projection + skip + LayerNorm + residual, grouped =================

__global__ __launch_bounds__(128) void k_out_g(
        const float* __restrict__ agg, float* __restrict__ h,
        const int* __restrict__ perm, const int* __restrict__ ntype,
        const float* __restrict__ Wa, const float* __restrict__ skip,
        const float* __restrict__ ln_g, const float* __restrict__ ln_b, int n) {
    int o = threadIdx.x;
    int base = blockIdx.x * GN;
    __shared__ float xs[GN][DIM];
    __shared__ float hcs[GN][DIM + 1];
    __shared__ int nodes[GN];
    __shared__ int types[GN];
    __shared__ float mu_s[GN], rs_s[GN];
    if (o < GN) {
        int idx = base + o;
        int nd = (idx < n) ? perm[idx] : -1;
        nodes[o] = nd;
        types[o] = (nd >= 0) ? ntype[nd] : -1;
    }
    __syncthreads();
    #pragma unroll
    for (int nn = 0; nn < GN; nn++)
        if (nodes[nn] >= 0) xs[nn][o] = agg[(size_t)nodes[nn] * DIM + o];
    __syncthreads();
    bool same = (nodes[GN - 1] >= 0) && (types[0] == types[GN - 1]);
    if (same) {
        int t = types[0];
        const float* w = Wa + (size_t)t * DIM * DIM;
        float acc[GN];
        #pragma unroll
        for (int nn = 0; nn < GN; nn++) acc[nn] = 0.f;
        for (int d = 0; d < DIM; d++) {
            float wv = w[d * DIM + o];
            #pragma unroll
            for (int nn = 0; nn < GN; nn++) acc[nn] = fmaf(xs[nn][d], wv, acc[nn]);
        }
        float alpha = 1.f / (1.f + __expf(-skip[t]));
        #pragma unroll
        for (int nn = 0; nn < GN; nn++) {
            float hp = h[(size_t)nodes[nn] * DIM + o];
            hcs[nn][o] = acc[nn] * alpha + hp * (1.f - alpha);
        }
    } else {
        #pragma unroll 1
        for (int nn = 0; nn < GN; nn++) {
            if (nodes[nn] < 0) continue;
            int t = types[nn];
            const float* w = Wa + (size_t)t * DIM * DIM;
            float a0 = 0.f;
            for (int d = 0; d < DIM; d++) a0 = fmaf(xs[nn][d], w[d * DIM + o], a0);
            float alpha = 1.f / (1.f + __expf(-skip[t]));
            float hp = h[(size_t)nodes[nn] * DIM + o];
            hcs[nn][o] = a0 * alpha + hp * (1.f - alpha);
        }
    }
    __syncthreads();
    {
        int g = o >> 4, j = o & 15;    // 8 groups x 16 lanes
        if (nodes[g] >= 0) {
            float s = 0.f;
            for (int d = j; d < DIM; d += 16) s += hcs[g][d];
            #pragma unroll
            for (int m = 1; m < 16; m <<= 1) s += __shfl_xor(s, m);
            float mu = s * (1.f / DIM);
            float v = 0.f;
            for (int d = j; d < DIM; d += 16) { float dv = hcs[g][d] - mu; v = fmaf(dv, dv, v); }
            #pragma unroll
            for (int m = 1; m < 16; m <<= 1) v += __shfl_xor(v, m);
            if (j == 0) { mu_s[g] = mu; rs_s[g] = rsqrtf(v * (1.f / DIM) + 1e-5f); }
        }
    }
    __syncthreads();
    float g_o = ln_g[o], b_o = ln_b[o];
    #pragma unroll
    for (int nn = 0; nn < GN; nn++) {
        if (nodes[nn] >= 0) {
            float hp = h[(size_t)nodes[nn] * DIM + o];
            h[(size_t)nodes[nn] * DIM + o] = (hcs[nn][o] - mu_s[nn]) * rs_s[nn] * g_o + b_o + hp;
        }
    }
}

// ================= host =================

extern "C" void kernel_launch(void* const* d_in, const int* in_sizes, int n_in,
                              void* d_out, int out_size, void* d_ws, size_t ws_size,
                              hipStream_t stream) {
    const float* embed = (const float*)d_in[0];
    const float* Wk    = (const float*)d_in[1];
    const float* Wq    = (const float*)d_in[2];
    const float* Wv    = (const float*)d_in[3];
    const float* Wa    = (const float*)d_in[4];
    const float* ratt  = (const float*)d_in[5];
    const float* rmsg  = (const float*)d_in[6];
    const float* rpri  = (const float*)d_in[7];
    const float* skip  = (const float*)d_in[8];
    const float* ln_g  = (const float*)d_in[9];
    const float* ln_b  = (const float*)d_in[10];
    const int*   src   = (const int*)d_in[11];
    const int*   dst   = (const int*)d_in[12];
    const int*   ntype = (const int*)d_in[13];
    const int*   etype = (const int*)d_in[14];

    float* h = (float*)d_out;

    const size_t ND = (size_t)N_NODES * DIM;
    const int nb = (N_NODES + RB - 1) / RB;
    unsigned short* kb = (unsigned short*)d_ws;          // N*128 bf16
    float* qbuf = (float*)(kb + ND);                     // N*128 fp32
    float* vbuf = qbuf + ND;                             // N*128 fp32
    int* rs2  = (int*)(vbuf + ND);               // NK+1
    int* deg2 = rs2 + (NK + 1);                  // NK
    int* cur2 = deg2 + NK;                       // NK
    int* epk  = cur2 + NK;                       // E
    int* bsum = epk + NEDGE;                     // 2048
    int* rank = bsum + 2048;                     // N
    int* hist = rank + N_NODES;                  // nb*NTYPE
    int* boff = hist + nb * NTYPE;               // nb*NTYPE
    int* typeoff = boff + nb * NTYPE;            // NTYPE
    int* perm = typeoff + NTYPE;                 // N
    float* rmsgT = (float*)(perm + N_NODES);     // L*H*R*256 fp32
    unsigned short* rattB = (unsigned short*)(rmsgT + (size_t)NLAYER * NHEAD * NREL * 256);  // L*H*R*256 bf16
    unsigned short* vt = rattB + (size_t)NLAYER * NHEAD * NREL * 256;   // N*R*128 bf16
    float* agg = qbuf;                           // alias: block reads its q rows, then writes agg rows

    const int EB = (NEDGE + 255) / 256;
    const int nb2 = (NK + 255) / 256;

    // ---- init: rank-within-type, embedding, type permutation ----
    k_hist<<<nb, RB, 0, stream>>>(ntype, hist, N_NODES);
    k_prefix<<<1, 64, 0, stream>>>(hist, boff, nb);
    k_rank<<<nb, RB, 0, stream>>>(ntype, boff, rank, N_NODES);
    k_embed<<<N_NODES, DIM, 0, stream>>>(embed, ntype, rank, h);
    k_typeoff<<<1, 64, 0, stream>>>(hist, boff, nb, typeoff);
    k_perm<<<nb, 256, 0, stream>>>(ntype, rank, typeoff, perm, N_NODES);

    // ---- (dst,etype)-sorted CSR build (graph static across layers) ----
    hipMemsetAsync(deg2, 0, (size_t)NK * sizeof(int), stream);
    hipMemsetAsync(cur2, 0, (size_t)NK * sizeof(int), stream);
    k_deg2<<<EB, 256, 0, stream>>>(dst, etype, deg2);
    k_scan1<<<nb2, 256, 0, stream>>>(deg2, rs2, bsum, NK);
    k_scan2b<<<1, 256, 0, stream>>>(bsum, nb2);
    k_scan3<<<nb2, 256, 0, stream>>>(rs2, bsum, NK);
    k_scatter2<<<EB, 256, 0, stream>>>(src, dst, etype, rs2, cur2, epk);

    // ---- weight prep (all layers) ----
    k_rmsgT<<<NLAYER * NHEAD * NREL, 256, 0, stream>>>(rmsg, rmsgT);
    k_rattB<<<NLAYER * NHEAD * NREL, 256, 0, stream>>>(ratt, rattB);

    const int NGB = N_NODES / GN;   // 6250

    for (int l = 0; l < NLAYER; l++) {
        const float* Wk_l = Wk + (size_t)l * NTYPE * DIM * DIM;
        const float* Wq_l = Wq + (size_t)l * NTYPE * DIM * DIM;
        const float* Wv_l = Wv + (size_t)l * NTYPE * DIM * DIM;
        const float* Wa_l = Wa + (size_t)l * NTYPE * DIM * DIM;
        const unsigned short* rattB_l = rattB + (size_t)l * NHEAD * NREL * 256;
        const float* rmsgT_l = rmsgT + (size_t)l * NHEAD * NREL * 256;
        const float* rpri_l = rpri + (size_t)l * NHEAD * NREL;
        const float* skip_l = skip + (size_t)l * NTYPE;
        const float* g_l = ln_g + (size_t)l * DIM;
        const float* b_l = ln_b + (size_t)l * DIM;

        k_qkv_g<<<NGB, 128, 0, stream>>>(h, perm, ntype, Wk_l, Wq_l, Wv_l,
                                         kb, qbuf, vbuf, N_NODES);
        k_vt<<<NGB, 128, 0, stream>>>(vbuf, rmsgT_l, vt);
        k_fused9<<<N_NODES / 2, 128, 0, stream>>>(kb, qbuf, vt, rs2, epk,
                                                  rattB_l, rpri_l, agg);
        k_out_g<<<NGB, 128, 0, stream>>>(agg, h, perm, ntype, Wa_l, skip_l, g_l, b_l, N_NODES);
    }
}

// Round 11
// 749.727 us; speedup vs baseline: 1.8045x; 1.3213x over previous
//
#include <hip/hip_runtime.h>
#include <math.h>

#define N_NODES 50000
#define DIM     128
#define NHEAD   8
#define HDIM    16
#define NLAYER  2
#define NTYPE   4
#define NREL    8
#define NEDGE   800000
#define RB      256
#define GN      8      // nodes per block in grouped kernels
#define NK      (N_NODES * NREL)

__device__ __forceinline__ float blo(unsigned w) { return __uint_as_float(w << 16); }
__device__ __forceinline__ float bhi(unsigned w) { return __uint_as_float(w & 0xFFFF0000u); }
__device__ __forceinline__ unsigned short f2bf(float f) {
    unsigned b = __float_as_uint(f);
    b += 0x7FFFu + ((b >> 16) & 1u);
    return (unsigned short)(b >> 16);
}

// ================= init: rank within type =================

__global__ void k_hist(const int* __restrict__ ntype, int* __restrict__ hist, int n) {
    __shared__ int cnt[NTYPE];
    if (threadIdx.x < NTYPE) cnt[threadIdx.x] = 0;
    __syncthreads();
    int i = blockIdx.x * RB + threadIdx.x;
    if (i < n) atomicAdd(&cnt[ntype[i]], 1);
    __syncthreads();
    if (threadIdx.x < NTYPE) hist[blockIdx.x * NTYPE + threadIdx.x] = cnt[threadIdx.x];
}

__global__ void k_prefix(const int* __restrict__ hist, int* __restrict__ off, int nb) {
    int t = threadIdx.x;
    if (t >= NTYPE) return;
    int acc = 0;
    for (int b = 0; b < nb; b++) { off[b * NTYPE + t] = acc; acc += hist[b * NTYPE + t]; }
}

__global__ void k_rank(const int* __restrict__ ntype, const int* __restrict__ off,
                       int* __restrict__ rank, int n) {
    __shared__ int ty[RB];
    int i = blockIdx.x * RB + threadIdx.x;
    int t = (i < n) ? ntype[i] : -1;
    ty[threadIdx.x] = t;
    __syncthreads();
    if (i < n) {
        int c = 0;
        for (int j = 0; j < (int)threadIdx.x; j++) c += (ty[j] == t);
        rank[i] = off[blockIdx.x * NTYPE + t] + c;
    }
}

__global__ void k_embed(const float* __restrict__ embed, const int* __restrict__ ntype,
                        const int* __restrict__ rank, float* __restrict__ h) {
    int i = blockIdx.x;
    int t = ntype[i], r = rank[i];
    h[(size_t)i * DIM + threadIdx.x] = embed[((size_t)t * N_NODES + r) * DIM + threadIdx.x];
}

__global__ void k_typeoff(const int* __restrict__ hist, const int* __restrict__ boff,
                          int nb, int* __restrict__ typeoff) {
    if (threadIdx.x == 0 && blockIdx.x == 0) {
        int acc = 0;
        for (int t = 0; t < NTYPE; t++) {
            typeoff[t] = acc;
            acc += boff[(nb - 1) * NTYPE + t] + hist[(nb - 1) * NTYPE + t];
        }
    }
}

__global__ void k_perm(const int* __restrict__ ntype, const int* __restrict__ rank,
                       const int* __restrict__ typeoff, int* __restrict__ perm, int n) {
    int i = blockIdx.x * 256 + threadIdx.x;
    if (i < n) perm[typeoff[ntype[i]] + rank[i]] = i;
}

// ================= (dst,etype)-sorted CSR build =================

__global__ void k_deg2(const int* __restrict__ dst, const int* __restrict__ etype,
                       int* __restrict__ deg) {
    int e = blockIdx.x * 256 + threadIdx.x;
    if (e < NEDGE) atomicAdd(&deg[dst[e] * NREL + etype[e]], 1);
}

__global__ void k_scan1(const int* __restrict__ deg, int* __restrict__ rs,
                        int* __restrict__ bsum, int n) {
    __shared__ int sh[256];
    int i = blockIdx.x * 256 + threadIdx.x;
    int v = (i < n) ? deg[i] : 0;
    sh[threadIdx.x] = v;
    __syncthreads();
    for (int off = 1; off < 256; off <<= 1) {
        int x = (threadIdx.x >= off) ? sh[threadIdx.x - off] : 0;
        __syncthreads();
        sh[threadIdx.x] += x;
        __syncthreads();
    }
    if (i < n) rs[i] = sh[threadIdx.x] - v;
    if (threadIdx.x == 255) bsum[blockIdx.x] = sh[255];
}

__global__ void k_scan2b(int* __restrict__ bsum, int nb) {
    __shared__ int sh[256];
    __shared__ int carry;
    if (threadIdx.x == 0) carry = 0;
    __syncthreads();
    for (int base = 0; base < nb; base += 256) {
        int i = base + threadIdx.x;
        int v = (i < nb) ? bsum[i] : 0;
        sh[threadIdx.x] = v;
        __syncthreads();
        for (int off = 1; off < 256; off <<= 1) {
            int x = (threadIdx.x >= off) ? sh[threadIdx.x - off] : 0;
            __syncthreads();
            sh[threadIdx.x] += x;
            __syncthreads();
        }
        if (i < nb) bsum[i] = sh[threadIdx.x] - v + carry;
        __syncthreads();
        if (threadIdx.x == 0) carry += sh[255];
        __syncthreads();
    }
}

__global__ void k_scan3(int* __restrict__ rs, const int* __restrict__ bsum, int n) {
    int i = blockIdx.x * 256 + threadIdx.x;
    if (i < n) rs[i] += bsum[blockIdx.x];
    if (i == 0) rs[n] = NEDGE;
}

__global__ void k_scatter2(const int* __restrict__ src, const int* __restrict__ dst,
                           const int* __restrict__ etype, const int* __restrict__ rs,
                           int* __restrict__ cur, int* __restrict__ epk) {
    int e = blockIdx.x * 256 + threadIdx.x;
    if (e < NEDGE) {
        int et = etype[e];
        int key = dst[e] * NREL + et;
        int p = atomicAdd(&cur[key], 1);
        epk[rs[key] + p] = src[e] | (et << 24);
    }
}

// ================= weight prep: rmsgT transpose + bf16 ratt pack =================

__global__ void k_rmsgT(const float* __restrict__ rmsg, float* __restrict__ rmsgT) {
    int b = blockIdx.x;
    int d = threadIdx.x >> 4, o = threadIdx.x & 15;
    rmsgT[b * 256 + o * 16 + d] = rmsg[b * 256 + d * 16 + o];
}

__global__ void k_rattB(const float* __restrict__ ratt, unsigned short* __restrict__ rattB) {
    int i = blockIdx.x * 256 + threadIdx.x;
    rattB[i] = f2bf(ratt[i]);
}

// ======== fused typed k/q/v projection + vt build (v never leaves the block) ========
// Phase 1: k/q/v typed dots (GN same-type nodes). Phase 2: reuse xs LDS for v,
// apply W_msg per (et, node) and write bf16 vt directly.

__global__ __launch_bounds__(128) void k_qkvvt_g(
        const float* __restrict__ h, const int* __restrict__ perm, const int* __restrict__ ntype,
        const float* __restrict__ Wk, const float* __restrict__ Wq, const float* __restrict__ Wv,
        const float* __restrict__ rmsgT,
        unsigned short* __restrict__ kb, float* __restrict__ qout,
        unsigned short* __restrict__ vt, int n) {
    int o = threadIdx.x;
    int base = blockIdx.x * GN;
    __shared__ float xs[GN][DIM];
    __shared__ int nodes[GN];
    __shared__ int types[GN];
    if (o < GN) {
        int idx = base + o;
        int nd = (idx < n) ? perm[idx] : -1;
        nodes[o] = nd;
        types[o] = (nd >= 0) ? ntype[nd] : -1;
    }
    __syncthreads();
    #pragma unroll
    for (int nn = 0; nn < GN; nn++)
        if (nodes[nn] >= 0) xs[nn][o] = h[(size_t)nodes[nn] * DIM + o];
    __syncthreads();
    bool same = (nodes[GN - 1] >= 0) && (types[0] == types[GN - 1]);
    float av[GN];
    if (same) {
        int t = types[0];
        const float* wk = Wk + (size_t)t * DIM * DIM;
        const float* wq = Wq + (size_t)t * DIM * DIM;
        const float* wv = Wv + (size_t)t * DIM * DIM;
        float ak[GN], aq[GN];
        #pragma unroll
        for (int nn = 0; nn < GN; nn++) { ak[nn] = 0.f; aq[nn] = 0.f; av[nn] = 0.f; }
        for (int d = 0; d < DIM; d++) {
            float wkv = wk[d * DIM + o], wqv = wq[d * DIM + o], wvv = wv[d * DIM + o];
            #pragma unroll
            for (int nn = 0; nn < GN; nn++) {
                float xv = xs[nn][d];
                ak[nn] = fmaf(xv, wkv, ak[nn]);
                aq[nn] = fmaf(xv, wqv, aq[nn]);
                av[nn] = fmaf(xv, wvv, av[nn]);
            }
        }
        #pragma unroll
        for (int nn = 0; nn < GN; nn++) {
            size_t p = (size_t)nodes[nn] * DIM + o;
            kb[p] = f2bf(ak[nn]); qout[p] = aq[nn];
        }
    } else {
        #pragma unroll 1
        for (int nn = 0; nn < GN; nn++) {
            av[nn] = 0.f;
            if (nodes[nn] < 0) continue;
            int t = types[nn];
            const float* wk = Wk + (size_t)t * DIM * DIM;
            const float* wq = Wq + (size_t)t * DIM * DIM;
            const float* wv = Wv + (size_t)t * DIM * DIM;
            float ak = 0.f, aq = 0.f, avv = 0.f;
            for (int d = 0; d < DIM; d++) {
                float xv = xs[nn][d];
                ak = fmaf(xv, wk[d * DIM + o], ak);
                aq = fmaf(xv, wq[d * DIM + o], aq);
                avv = fmaf(xv, wv[d * DIM + o], avv);
            }
            size_t p = (size_t)nodes[nn] * DIM + o;
            kb[p] = f2bf(ak); qout[p] = aq;
            av[nn] = avv;
        }
    }
    // ---- phase 2: stage v into xs (h rows dead), build vt in-place ----
    __syncthreads();
    #pragma unroll
    for (int nn = 0; nn < GN; nn++) xs[nn][o] = av[nn];
    __syncthreads();
    int hh = o >> 4, oo = o & 15;
    #pragma unroll 1
    for (int et = 0; et < NREL; et++) {
        const float4* w4 = (const float4*)(rmsgT + ((size_t)(hh * NREL + et) * HDIM + oo) * HDIM);
        float4 w0 = w4[0], w1 = w4[1], w2 = w4[2], w3 = w4[3];
        #pragma unroll
        for (int nn = 0; nn < GN; nn++) {
            if (nodes[nn] < 0) continue;
            const float4* v4 = (const float4*)&xs[nn][hh * HDIM];
            float4 v0 = v4[0], v1 = v4[1], v2 = v4[2], v3 = v4[3];
            float acc = v0.x*w0.x + v0.y*w0.y + v0.z*w0.z + v0.w*w0.w
                      + v1.x*w1.x + v1.y*w1.y + v1.z*w1.z + v1.w*w1.w
                      + v2.x*w2.x + v2.y*w2.y + v2.z*w2.z + v2.w*w2.w
                      + v3.x*w3.x + v3.y*w3.y + v3.z*w3.z + v3.w*w3.w;
            vt[((size_t)nodes[nn] * NREL + et) * DIM + o] = f2bf(acc);
        }
    }
}

// ================= fused attention v10: fused5 skeleton + bf16 rattB ====
// 1 node/block (low VGPR, high occupancy), single accumulator, runtime pass-2 over vt,
// deferred-rescale online softmax, zero barriers in the edge loop.

__global__ __launch_bounds__(128) void k_fused10(
        const unsigned short* __restrict__ kb, const float* __restrict__ qbuf,
        const unsigned short* __restrict__ vt,
        const int* __restrict__ rs2, const int* __restrict__ epk,
        const unsigned short* __restrict__ rattB, const float* __restrict__ rpri,
        float* __restrict__ agg) {
    int node = blockIdx.x;
    int tid = threadIdx.x;
    int hh = tid >> 4, oo = tid & 15;
    int wv = tid >> 6;            // wave id (heads 0-3 | 4-7)
    int hl = hh & 3;              // head local to wave

    __shared__ float q_s[DIM];
    __shared__ float u_s[NREL][NHEAD * HDIM + 4];   // stride 132, 16B-aligned rows
    __shared__ float a_sw[2][4][HDIM + 1];          // per-wave p scratch
    __shared__ int   es_sw[2][HDIM];                // per-wave packed-edge scratch

    int e0 = rs2[node * NREL];
    int e1 = rs2[node * NREL + NREL];
    if (e0 == e1) { agg[(size_t)node * DIM + tid] = 0.f; return; }

    q_s[tid] = qbuf[(size_t)node * DIM + tid];
    // u_s[et][hh*16+d] = (rattB[hh][et][d][:] . q_h) * pri * 0.25  (lane d = oo)
    {
        const float4* q4 = (const float4*)&q_s[hh * HDIM];   // intra-group LDS, in-order
        float4 q0 = q4[0], q1 = q4[1], q2 = q4[2], q3 = q4[3];
        #pragma unroll
        for (int et = 0; et < NREL; et++) {
            const uint4* wB = (const uint4*)(rattB + ((size_t)(hh * NREL + et) * HDIM + oo) * HDIM);
            uint4 wa = wB[0], wb = wB[1];
            float s = blo(wa.x)*q0.x + bhi(wa.x)*q0.y + blo(wa.y)*q0.z + bhi(wa.y)*q0.w
                    + blo(wa.z)*q1.x + bhi(wa.z)*q1.y + blo(wa.w)*q1.z + bhi(wa.w)*q1.w
                    + blo(wb.x)*q2.x + bhi(wb.x)*q2.y + blo(wb.y)*q2.z + bhi(wb.y)*q2.w
                    + blo(wb.z)*q3.x + bhi(wb.z)*q3.y + blo(wb.w)*q3.z + bhi(wb.w)*q3.w;
            u_s[et][tid] = s * rpri[hh * NREL + et] * 0.25f;
        }
    }

    float m_h = -1e30f, s_h = 0.f, out = 0.f;

    for (int w0e = e0; w0e < e1; w0e += HDIM) {
        int cnt = min(HDIM, e1 - w0e);
        // ---- pass 1: logits + deferred-rescale online softmax ----
        float a = -1e30f;
        int pk = 0;
        if (oo < cnt) {
            pk = epk[w0e + oo];
            int sv = pk & 0x00FFFFFF;
            int et = ((unsigned)pk) >> 24;
            const uint4* kr = (const uint4*)(kb + (size_t)sv * DIM + hh * HDIM);
            uint4 ka = kr[0], kc = kr[1];
            const float4* u4 = (const float4*)&u_s[et][hh * HDIM];
            float4 u0 = u4[0], u1 = u4[1], u2 = u4[2], u3 = u4[3];
            a = blo(ka.x)*u0.x + bhi(ka.x)*u0.y + blo(ka.y)*u0.z + bhi(ka.y)*u0.w
              + blo(ka.z)*u1.x + bhi(ka.z)*u1.y + blo(ka.w)*u1.z + bhi(ka.w)*u1.w
              + blo(kc.x)*u2.x + bhi(kc.x)*u2.y + blo(kc.y)*u2.z + bhi(kc.y)*u2.w
              + blo(kc.z)*u3.x + bhi(kc.z)*u3.y + blo(kc.w)*u3.z + bhi(kc.w)*u3.w;
        }
        if (hl == 0) es_sw[wv][oo] = pk;
        float cmax = a;
        cmax = fmaxf(cmax, __shfl_xor(cmax, 1));
        cmax = fmaxf(cmax, __shfl_xor(cmax, 2));
        cmax = fmaxf(cmax, __shfl_xor(cmax, 4));
        cmax = fmaxf(cmax, __shfl_xor(cmax, 8));
        float m_t = (cmax > m_h + 12.f) ? cmax : m_h;   // deferred rescale (THR=12)
        float r = __expf(m_h - m_t);                    // ==1 when not triggered
        s_h *= r; out *= r; m_h = m_t;
        float p = (oo < cnt) ? __expf(a - m_h) : 0.f;
        float ps = p;
        ps += __shfl_xor(ps, 1);
        ps += __shfl_xor(ps, 2);
        ps += __shfl_xor(ps, 4);
        ps += __shfl_xor(ps, 8);
        s_h += ps;
        a_sw[wv][hl][oo] = p;
        // ---- pass 2: runtime-bounded homogeneous loop (fused5 schedule) ----
        for (int c = 0; c < cnt; c++) {
            float pc = a_sw[wv][hl][c];        // group broadcast
            int pkc = es_sw[wv][c];            // wave broadcast
            int sv = pkc & 0x00FFFFFF;
            int et = ((unsigned)pkc) >> 24;
            unsigned short uv = vt[((size_t)sv * NREL + et) * DIM + tid];
            out = fmaf(pc, __uint_as_float((unsigned)uv << 16), out);
        }
    }

    agg[(size_t)node * DIM + tid] = out / (s_h + 1e-9f);
}

// ================= output projection + skip + LayerNorm + residual, grouped =================

__global__ __launch_bounds__(128) void k_out_g(
        const float* __restrict__ agg, float* __restrict__ h,
        const int* __restrict__ perm, const int* __restrict__ ntype,
        const float* __restrict__ Wa, const float* __restrict__ skip,
        const float* __restrict__ ln_g, const float* __restrict__ ln_b, int n) {
    int o = threadIdx.x;
    int base = blockIdx.x * GN;
    __shared__ float xs[GN][DIM];
    __shared__ float hcs[GN][DIM + 1];
    __shared__ int nodes[GN];
    __shared__ int types[GN];
    __shared__ float mu_s[GN], rs_s[GN];
    if (o < GN) {
        int idx = base + o;
        int nd = (idx < n) ? perm[idx] : -1;
        nodes[o] = nd;
        types[o] = (nd >= 0) ? ntype[nd] : -1;
    }
    __syncthreads();
    #pragma unroll
    for (int nn = 0; nn < GN; nn++)
        if (nodes[nn] >= 0) xs[nn][o] = agg[(size_t)nodes[nn] * DIM + o];
    __syncthreads();
    bool same = (nodes[GN - 1] >= 0) && (types[0] == types[GN - 1]);
    if (same) {
        int t = types[0];
        const float* w = Wa + (size_t)t * DIM * DIM;
        float acc[GN];
        #pragma unroll
        for (int nn = 0; nn < GN; nn++) acc[nn] = 0.f;
        for (int d = 0; d < DIM; d++) {
            float wv = w[d * DIM + o];
            #pragma unroll
            for (int nn = 0; nn < GN; nn++) acc[nn] = fmaf(xs[nn][d], wv, acc[nn]);
        }
        float alpha = 1.f / (1.f + __expf(-skip[t]));
        #pragma unroll
        for (int nn = 0; nn < GN; nn++) {
            float hp = h[(size_t)nodes[nn] * DIM + o];
            hcs[nn][o] = acc[nn] * alpha + hp * (1.f - alpha);
        }
    } else {
        #pragma unroll 1
        for (int nn = 0; nn < GN; nn++) {
            if (nodes[nn] < 0) continue;
            int t = types[nn];
            const float* w = Wa + (size_t)t * DIM * DIM;
            float a0 = 0.f;
            for (int d = 0; d < DIM; d++) a0 = fmaf(xs[nn][d], w[d * DIM + o], a0);
            float alpha = 1.f / (1.f + __expf(-skip[t]));
            float hp = h[(size_t)nodes[nn] * DIM + o];
            hcs[nn][o] = a0 * alpha + hp * (1.f - alpha);
        }
    }
    __syncthreads();
    {
        int g = o >> 4, j = o & 15;    // 8 groups x 16 lanes
        if (nodes[g] >= 0) {
            float s = 0.f;
            for (int d = j; d < DIM; d += 16) s += hcs[g][d];
            #pragma unroll
            for (int m = 1; m < 16; m <<= 1) s += __shfl_xor(s, m);
            float mu = s * (1.f / DIM);
            float v = 0.f;
            for (int d = j; d < DIM; d += 16) { float dv = hcs[g][d] - mu; v = fmaf(dv, dv, v); }
            #pragma unroll
            for (int m = 1; m < 16; m <<= 1) v += __shfl_xor(v, m);
            if (j == 0) { mu_s[g] = mu; rs_s[g] = rsqrtf(v * (1.f / DIM) + 1e-5f); }
        }
    }
    __syncthreads();
    float g_o = ln_g[o], b_o = ln_b[o];
    #pragma unroll
    for (int nn = 0; nn < GN; nn++) {
        if (nodes[nn] >= 0) {
            float hp = h[(size_t)nodes[nn] * DIM + o];
            h[(size_t)nodes[nn] * DIM + o] = (hcs[nn][o] - mu_s[nn]) * rs_s[nn] * g_o + b_o + hp;
        }
    }
}

// ================= host =================

extern "C" void kernel_launch(void* const* d_in, const int* in_sizes, int n_in,
                              void* d_out, int out_size, void* d_ws, size_t ws_size,
                              hipStream_t stream) {
    const float* embed = (const float*)d_in[0];
    const float* Wk    = (const float*)d_in[1];
    const float* Wq    = (const float*)d_in[2];
    const float* Wv    = (const float*)d_in[3];
    const float* Wa    = (const float*)d_in[4];
    const float* ratt  = (const float*)d_in[5];
    const float* rmsg  = (const float*)d_in[6];
    const float* rpri  = (const float*)d_in[7];
    const float* skip  = (const float*)d_in[8];
    const float* ln_g  = (const float*)d_in[9];
    const float* ln_b  = (const float*)d_in[10];
    const int*   src   = (const int*)d_in[11];
    const int*   dst   = (const int*)d_in[12];
    const int*   ntype = (const int*)d_in[13];
    const int*   etype = (const int*)d_in[14];

    float* h = (float*)d_out;

    const size_t ND = (size_t)N_NODES * DIM;
    const int nb = (N_NODES + RB - 1) / RB;
    unsigned short* kb = (unsigned short*)d_ws;          // N*128 bf16
    float* qbuf = (float*)(kb + ND);                     // N*128 fp32
    int* rs2  = (int*)(qbuf + ND);               // NK+1
    int* deg2 = rs2 + (NK + 1);                  // NK
    int* cur2 = deg2 + NK;                       // NK
    int* epk  = cur2 + NK;                       // E
    int* bsum = epk + NEDGE;                     // 2048
    int* rank = bsum + 2048;                     // N
    int* hist = rank + N_NODES;                  // nb*NTYPE
    int* boff = hist + nb * NTYPE;               // nb*NTYPE
    int* typeoff = boff + nb * NTYPE;            // NTYPE
    int* perm = typeoff + NTYPE;                 // N
    float* rmsgT = (float*)(perm + N_NODES);     // L*H*R*256 fp32
    unsigned short* rattB = (unsigned short*)(rmsgT + (size_t)NLAYER * NHEAD * NREL * 256);  // bf16
    unsigned short* vt = rattB + (size_t)NLAYER * NHEAD * NREL * 256;   // N*R*128 bf16
    float* agg = qbuf;                           // alias: block reads its q row, then writes agg row

    const int EB = (NEDGE + 255) / 256;
    const int nb2 = (NK + 255) / 256;

    // ---- init: rank-within-type, embedding, type permutation ----
    k_hist<<<nb, RB, 0, stream>>>(ntype, hist, N_NODES);
    k_prefix<<<1, 64, 0, stream>>>(hist, boff, nb);
    k_rank<<<nb, RB, 0, stream>>>(ntype, boff, rank, N_NODES);
    k_embed<<<N_NODES, DIM, 0, stream>>>(embed, ntype, rank, h);
    k_typeoff<<<1, 64, 0, stream>>>(hist, boff, nb, typeoff);
    k_perm<<<nb, 256, 0, stream>>>(ntype, rank, typeoff, perm, N_NODES);

    // ---- (dst,etype)-sorted CSR build (graph static across layers) ----
    hipMemsetAsync(deg2, 0, (size_t)NK * sizeof(int), stream);
    hipMemsetAsync(cur2, 0, (size_t)NK * sizeof(int), stream);
    k_deg2<<<EB, 256, 0, stream>>>(dst, etype, deg2);
    k_scan1<<<nb2, 256, 0, stream>>>(deg2, rs2, bsum, NK);
    k_scan2b<<<1, 256, 0, stream>>>(bsum, nb2);
    k_scan3<<<nb2, 256, 0, stream>>>(rs2, bsum, NK);
    k_scatter2<<<EB, 256, 0, stream>>>(src, dst, etype, rs2, cur2, epk);

    // ---- weight prep (all layers) ----
    k_rmsgT<<<NLAYER * NHEAD * NREL, 256, 0, stream>>>(rmsg, rmsgT);
    k_rattB<<<NLAYER * NHEAD * NREL, 256, 0, stream>>>(ratt, rattB);

    const int NGB = N_NODES / GN;   // 6250

    for (int l = 0; l < NLAYER; l++) {
        const float* Wk_l = Wk + (size_t)l * NTYPE * DIM * DIM;
        const float* Wq_l = Wq + (size_t)l * NTYPE * DIM * DIM;
        const float* Wv_l = Wv + (size_t)l * NTYPE * DIM * DIM;
        const float* Wa_l = Wa + (size_t)l * NTYPE * DIM * DIM;
        const unsigned short* rattB_l = rattB + (size_t)l * NHEAD * NREL * 256;
        const float* rmsgT_l = rmsgT + (size_t)l * NHEAD * NREL * 256;
        const float* rpri_l = rpri + (size_t)l * NHEAD * NREL;
        const float* skip_l = skip + (size_t)l * NTYPE;
        const float* g_l = ln_g + (size_t)l * DIM;
        const float* b_l = ln_b + (size_t)l * DIM;

        k_qkvvt_g<<<NGB, 128, 0, stream>>>(h, perm, ntype, Wk_l, Wq_l, Wv_l, rmsgT_l,
                                           kb, qbuf, vt, N_NODES);
        k_fused10<<<N_NODES, 128, 0, stream>>>(kb, qbuf, vt, rs2, epk,
                                               rattB_l, rpri_l, agg);
        k_out_g<<<NGB, 128, 0, stream>>>(agg, h, perm, ntype, Wa_l, skip_l, g_l, b_l, N_NODES);
    }
}